// Round 11
// baseline (96.592 us; speedup 1.0000x reference)
//
#include <hip/hip_runtime.h>

#define Hn 768
#define Bn 16
#define Sn 512
#define En 32
#define Vn 50265

#define KC   4            // k-chunks (split-K across blocks)
#define KPC  (Hn / KC)    // 192 k per chunk
#define KPW  (KPC / 4)    // 48 k per wave (4 waves/block)
#define VPB  128          // v per block

// ---------------- out[b][v] = lm_b[v]  (bias init; lm_head atomics accumulate on top;
// also required for determinism: harness does not clear out between timed replays)
__global__ __launch_bounds__(256) void out_init(
    const float* __restrict__ lm_b, float* __restrict__ out)
{
    const int v = blockIdx.x * 256 + threadIdx.x;
    if (v < Vn) out[(size_t)blockIdx.y * Vn + v] = lm_b[v];
}

// ---------------- Layer 1: o1 = g1*inst + (1-g1)*sent, g1 = sigmoid(inst@W1_1 + sent@W1_2)
__global__ __launch_bounds__(256) void gate_layer1(
    const int* __restrict__ batch_arg, const int* __restrict__ event_pos,
    const int* __restrict__ mask_indices, const float* __restrict__ sent_emb,
    const float* __restrict__ emb_table, const float* __restrict__ W1_1,
    const float* __restrict__ W1_2, float* __restrict__ o1_out)
{
    const int b  = blockIdx.x;
    const int j0 = threadIdx.x & 63;
    const int ks = threadIdx.x >> 6;           // wave-uniform
    const int j  = blockIdx.y * 64 + j0;

    const int mask = mask_indices[b];
    int estar = -1;
    #pragma unroll
    for (int e = 0; e < En; ++e)
        if (event_pos[b * En + e] == mask && estar < 0) estar = e;
    const int tok = batch_arg[b * Sn + mask];

    __shared__ __align__(16) float s_inst[Hn];
    __shared__ __align__(16) float s_sent[Hn];
    for (int t = threadIdx.x; t < Hn; t += 256) {
        s_inst[t] = emb_table[(size_t)tok * Hn + t];
        s_sent[t] = (estar >= 0) ? sent_emb[((size_t)b * En + estar) * Hn + t] : 0.f;
    }
    __syncthreads();

    float a0 = 0.f, a1 = 0.f, c0 = 0.f, c1 = 0.f;
    const float* __restrict__ w1 = W1_1 + (size_t)ks * 192 * Hn + j;
    const float* __restrict__ w2 = W1_2 + (size_t)ks * 192 * Hn + j;
    const float4* __restrict__ si = (const float4*)(s_inst + ks * 192);
    const float4* __restrict__ ss = (const float4*)(s_sent + ks * 192);
    #pragma unroll 4
    for (int k4 = 0; k4 < 48; ++k4) {
        const float4 iv = si[k4];
        const float4 sv = ss[k4];
        const float* __restrict__ wa = w1 + (size_t)k4 * 4 * Hn;
        const float* __restrict__ wb = w2 + (size_t)k4 * 4 * Hn;
        a0 = fmaf(iv.x, wa[0],      a0);
        a1 = fmaf(iv.y, wa[Hn],     a1);
        a0 = fmaf(iv.z, wa[2 * Hn], a0);
        a1 = fmaf(iv.w, wa[3 * Hn], a1);
        c0 = fmaf(sv.x, wb[0],      c0);
        c1 = fmaf(sv.y, wb[Hn],     c1);
        c0 = fmaf(sv.z, wb[2 * Hn], c0);
        c1 = fmaf(sv.w, wb[3 * Hn], c1);
    }

    __shared__ float r_a[4][64];
    __shared__ float r_c[4][64];
    r_a[ks][j0] = a0 + a1; r_c[ks][j0] = c0 + c1;
    __syncthreads();
    if (ks == 0) {
        const float A = r_a[0][j0] + r_a[1][j0] + r_a[2][j0] + r_a[3][j0];
        const float C = r_c[0][j0] + r_c[1][j0] + r_c[2][j0] + r_c[3][j0];
        const float g = 1.f / (1.f + expf(-(A + C)));
        o1_out[b * Hn + j] = g * s_inst[j] + (1.f - g) * s_sent[j];
    }
}

// ---------------- Layer 2: o2 = g2*o1 + (1-g2)*typ, written TRANSPOSED as me_t[k][b]
__global__ __launch_bounds__(256) void gate_layer2(
    const int* __restrict__ batch_arg, const int* __restrict__ event_pos,
    const int* __restrict__ mask_indices, const float* __restrict__ type_emb,
    const float* __restrict__ emb_table, const float* __restrict__ W2_1,
    const float* __restrict__ W2_2, const float* __restrict__ o1_in,
    float* __restrict__ me_t)
{
    const int b  = blockIdx.x;
    const int j0 = threadIdx.x & 63;
    const int ks = threadIdx.x >> 6;
    const int j  = blockIdx.y * 64 + j0;

    const int mask = mask_indices[b];
    int estar = -1;
    #pragma unroll
    for (int e = 0; e < En; ++e)
        if (event_pos[b * En + e] == mask && estar < 0) estar = e;
    const int tok = batch_arg[b * Sn + mask];

    __shared__ __align__(16) float s_o1[Hn];
    __shared__ __align__(16) float s_typ[Hn];
    for (int t = threadIdx.x; t < Hn; t += 256) {
        s_o1[t]  = o1_in[b * Hn + t];
        s_typ[t] = type_emb[((size_t)b * Sn + mask) * Hn + t];
    }
    __syncthreads();

    float a0 = 0.f, a1 = 0.f, c0 = 0.f, c1 = 0.f;
    const float* __restrict__ w1 = W2_1 + (size_t)ks * 192 * Hn + j;
    const float* __restrict__ w2 = W2_2 + (size_t)ks * 192 * Hn + j;
    const float4* __restrict__ so = (const float4*)(s_o1  + ks * 192);
    const float4* __restrict__ st = (const float4*)(s_typ + ks * 192);
    #pragma unroll 4
    for (int k4 = 0; k4 < 48; ++k4) {
        const float4 ov = so[k4];
        const float4 tv = st[k4];
        const float* __restrict__ wa = w1 + (size_t)k4 * 4 * Hn;
        const float* __restrict__ wb = w2 + (size_t)k4 * 4 * Hn;
        a0 = fmaf(ov.x, wa[0],      a0);
        a1 = fmaf(ov.y, wa[Hn],     a1);
        a0 = fmaf(ov.z, wa[2 * Hn], a0);
        a1 = fmaf(ov.w, wa[3 * Hn], a1);
        c0 = fmaf(tv.x, wb[0],      c0);
        c1 = fmaf(tv.y, wb[Hn],     c1);
        c0 = fmaf(tv.z, wb[2 * Hn], c0);
        c1 = fmaf(tv.w, wb[3 * Hn], c1);
    }

    __shared__ float r_a[4][64];
    __shared__ float r_c[4][64];
    r_a[ks][j0] = a0 + a1; r_c[ks][j0] = c0 + c1;
    __syncthreads();
    if (ks == 0) {
        const float A = r_a[0][j0] + r_a[1][j0] + r_a[2][j0] + r_a[3][j0];
        const float C = r_c[0][j0] + r_c[1][j0] + r_c[2][j0] + r_c[3][j0];
        const float g = 1.f / (1.f + expf(-(A + C)));
        float o2 = g * s_o1[j] + (1.f - g) * s_typ[j];
        if (estar < 0) o2 = emb_table[(size_t)tok * Hn + j];  // mask row never updated
        me_t[j * Bn + b] = o2;
    }
}

// ---------------- LM head, split-K: out[b][v] += sum_{k in chunk} me_t[k][b]*lm_W[k][v]
// Grid (393, 4) = 1572 blocks x 256 threads -> ~6 blocks/CU, balanced; 28 KB LDS
// -> 5 blocks/CU resident = 20 streaming waves/CU (vs 16 before in 1.53 rounds).
// Thread = 4 v (float4 W) x 8 b; per k: 1 float4 W + 2 ds_read_b128 + 32 fmaf.
// Two-pass LDS reduce (16 KB), then atomicAdd into bias-initialized out.
__global__ __launch_bounds__(256) void lm_head_splitk(
    const float* __restrict__ me_t, const float* __restrict__ lm_W,
    float* __restrict__ out)
{
    __shared__ __align__(16) float s_me[KPC * Bn];     // 12 KB: me slice for this k-chunk
    __shared__ __align__(16) float red[4][8][VPB];     // 16 KB: cross-wave reduce

    const int tid  = threadIdx.x;
    const int lane = tid & 63;
    const int w    = tid >> 6;                    // 0..3
    const int bh   = lane & 1;                    // b-half: 0 -> b0-7, 1 -> b8-15
    const int vq   = lane >> 1;                   // 0..31
    const int kc   = blockIdx.y;
    const int v0   = blockIdx.x * VPB + vq * 4;   // four consecutive v's

    // ---- stage me slice (192 k x 16 b = 12 KB), coalesced
    {
        const float4* __restrict__ src = (const float4*)(me_t + kc * KPC * Bn);
        float4* __restrict__ dst = (float4*)s_me;
        #pragma unroll
        for (int i = 0; i < 3; ++i)
            dst[i * 256 + tid] = src[i * 256 + tid];
    }
    __syncthreads();

    const int kb = kc * KPC + w * KPW;            // this wave's absolute k base
    float4 acc[8];
    #pragma unroll
    for (int i = 0; i < 8; ++i) acc[i] = make_float4(0.f, 0.f, 0.f, 0.f);

    const float* __restrict__ mb = s_me + (w * KPW) * Bn + bh * 8;

#define FMA32(wv, m0, m1)                                                     \
    acc[0].x = fmaf(m0.x, wv.x, acc[0].x); acc[0].y = fmaf(m0.x, wv.y, acc[0].y); \
    acc[0].z = fmaf(m0.x, wv.z, acc[0].z); acc[0].w = fmaf(m0.x, wv.w, acc[0].w); \
    acc[1].x = fmaf(m0.y, wv.x, acc[1].x); acc[1].y = fmaf(m0.y, wv.y, acc[1].y); \
    acc[1].z = fmaf(m0.y, wv.z, acc[1].z); acc[1].w = fmaf(m0.y, wv.w, acc[1].w); \
    acc[2].x = fmaf(m0.z, wv.x, acc[2].x); acc[2].y = fmaf(m0.z, wv.y, acc[2].y); \
    acc[2].z = fmaf(m0.z, wv.z, acc[2].z); acc[2].w = fmaf(m0.z, wv.w, acc[2].w); \
    acc[3].x = fmaf(m0.w, wv.x, acc[3].x); acc[3].y = fmaf(m0.w, wv.y, acc[3].y); \
    acc[3].z = fmaf(m0.w, wv.z, acc[3].z); acc[3].w = fmaf(m0.w, wv.w, acc[3].w); \
    acc[4].x = fmaf(m1.x, wv.x, acc[4].x); acc[4].y = fmaf(m1.x, wv.y, acc[4].y); \
    acc[4].z = fmaf(m1.x, wv.z, acc[4].z); acc[4].w = fmaf(m1.x, wv.w, acc[4].w); \
    acc[5].x = fmaf(m1.y, wv.x, acc[5].x); acc[5].y = fmaf(m1.y, wv.y, acc[5].y); \
    acc[5].z = fmaf(m1.y, wv.z, acc[5].z); acc[5].w = fmaf(m1.y, wv.w, acc[5].w); \
    acc[6].x = fmaf(m1.z, wv.x, acc[6].x); acc[6].y = fmaf(m1.z, wv.y, acc[6].y); \
    acc[6].z = fmaf(m1.z, wv.z, acc[6].z); acc[6].w = fmaf(m1.z, wv.w, acc[6].w); \
    acc[7].x = fmaf(m1.w, wv.x, acc[7].x); acc[7].y = fmaf(m1.w, wv.y, acc[7].y); \
    acc[7].z = fmaf(m1.w, wv.z, acc[7].z); acc[7].w = fmaf(m1.w, wv.w, acc[7].w);

    if (__all(v0 + 3 < Vn)) {
        const float* __restrict__ wp = lm_W + (size_t)kb * Vn + v0;
        #pragma unroll 4
        for (int k = 0; k < KPW; ++k) {
            const float4 wv = *(const float4*)(wp + (size_t)k * Vn);
            const float4 m0 = *(const float4*)(mb + k * Bn);
            const float4 m1 = *(const float4*)(mb + k * Bn + 4);
            FMA32(wv, m0, m1)
        }
    } else {
        // tail (last v-block only): clamped scalar loads; dup/OOB results never stored
        const float* __restrict__ wq = lm_W + (size_t)kb * Vn;
        const int vx0 = (v0     < Vn) ? v0     : (Vn - 1);
        const int vx1 = (v0 + 1 < Vn) ? v0 + 1 : (Vn - 1);
        const int vx2 = (v0 + 2 < Vn) ? v0 + 2 : (Vn - 1);
        const int vx3 = (v0 + 3 < Vn) ? v0 + 3 : (Vn - 1);
        for (int k = 0; k < KPW; ++k) {
            float4 wv;
            wv.x = wq[(size_t)k * Vn + vx0];
            wv.y = wq[(size_t)k * Vn + vx1];
            wv.z = wq[(size_t)k * Vn + vx2];
            wv.w = wq[(size_t)k * Vn + vx3];
            const float4 m0 = *(const float4*)(mb + k * Bn);
            const float4 m1 = *(const float4*)(mb + k * Bn + 4);
            FMA32(wv, m0, m1)
        }
    }
#undef FMA32

    // ---- two-pass cross-wave reduce + atomic accumulate
    #pragma unroll
    for (int half = 0; half < 2; ++half) {
        __syncthreads();
        if (bh == half) {
            #pragma unroll
            for (int i = 0; i < 8; ++i)
                *(float4*)&red[w][i][vq * 4] = acc[i];
        }
        __syncthreads();
        #pragma unroll
        for (int e = 0; e < 4; ++e) {
            const int j  = tid * 4 + e;           // 0..1023 = 8 b x 128 v
            const int bb = (j >> 7) + half * 8;
            const int l  = j & 127;
            const int vv = blockIdx.x * VPB + l;
            if (vv < Vn) {
                const float s = red[0][j >> 7][l] + red[1][j >> 7][l]
                              + red[2][j >> 7][l] + red[3][j >> 7][l];
                atomicAdd(&out[(size_t)bb * Vn + vv], s);
            }
        }
    }
}

extern "C" void kernel_launch(void* const* d_in, const int* in_sizes, int n_in,
                              void* d_out, int out_size, void* d_ws, size_t ws_size,
                              hipStream_t stream) {
    const int*   batch_arg    = (const int*)  d_in[0];
    const int*   event_pos    = (const int*)  d_in[1];
    const int*   mask_indices = (const int*)  d_in[2];
    const float* sent_emb     = (const float*)d_in[3];
    const float* type_emb     = (const float*)d_in[4];
    const float* emb_table    = (const float*)d_in[5];
    const float* W1_1         = (const float*)d_in[6];
    const float* W1_2         = (const float*)d_in[7];
    const float* W2_1         = (const float*)d_in[8];
    const float* W2_2         = (const float*)d_in[9];
    const float* lm_W         = (const float*)d_in[10];
    const float* lm_b         = (const float*)d_in[11];
    float* out = (float*)d_out;

    float* o1_ws = (float*)d_ws;                 // Bn*Hn floats
    float* me_t  = o1_ws + (size_t)Bn * Hn;      // Hn*Bn floats (16B aligned)

    dim3 gv((Vn + 255) / 256, Bn);
    out_init<<<gv, 256, 0, stream>>>(lm_b, out);

    dim3 g12(Bn, Hn / 64);
    gate_layer1<<<g12, 256, 0, stream>>>(batch_arg, event_pos, mask_indices,
                                         sent_emb, emb_table, W1_1, W1_2, o1_ws);
    gate_layer2<<<g12, 256, 0, stream>>>(batch_arg, event_pos, mask_indices,
                                         type_emb, emb_table, W2_1, W2_2, o1_ws, me_t);

    dim3 gh((Vn + VPB - 1) / VPB, KC);
    lm_head_splitk<<<gh, 256, 0, stream>>>(me_t, lm_W, out);
}

// Round 12
// 68.668 us; speedup vs baseline: 1.4067x; 1.4067x over previous
//
#include <hip/hip_runtime.h>

#define Hn 768
#define Bn 16
#define Sn 512
#define En 32
#define Vn 50265

#define KC   16           // k-chunks (split-K across blocks)
#define KPB  (Hn / KC)    // 48 k per block
#define VT   1024         // v per block (256 threads x 4 v) -> 4 KB/row/block
#define NVT  50           // v tiles (50 * 1024 = 51200 >= Vn)
#define VNP  (NVT * VT)   // padded V for partials

// ---------------- Layer 1: o1 = g1*inst + (1-g1)*sent, g1 = sigmoid(inst@W1_1 + sent@W1_2)
__global__ __launch_bounds__(256) void gate_layer1(
    const int* __restrict__ batch_arg, const int* __restrict__ event_pos,
    const int* __restrict__ mask_indices, const float* __restrict__ sent_emb,
    const float* __restrict__ emb_table, const float* __restrict__ W1_1,
    const float* __restrict__ W1_2, float* __restrict__ o1_out)
{
    const int b  = blockIdx.x;
    const int j0 = threadIdx.x & 63;
    const int ks = threadIdx.x >> 6;           // wave-uniform
    const int j  = blockIdx.y * 64 + j0;

    const int mask = mask_indices[b];
    int estar = -1;
    #pragma unroll
    for (int e = 0; e < En; ++e)
        if (event_pos[b * En + e] == mask && estar < 0) estar = e;
    const int tok = batch_arg[b * Sn + mask];

    __shared__ __align__(16) float s_inst[Hn];
    __shared__ __align__(16) float s_sent[Hn];
    for (int t = threadIdx.x; t < Hn; t += 256) {
        s_inst[t] = emb_table[(size_t)tok * Hn + t];
        s_sent[t] = (estar >= 0) ? sent_emb[((size_t)b * En + estar) * Hn + t] : 0.f;
    }
    __syncthreads();

    float a0 = 0.f, a1 = 0.f, c0 = 0.f, c1 = 0.f;
    const float* __restrict__ w1 = W1_1 + (size_t)ks * 192 * Hn + j;
    const float* __restrict__ w2 = W1_2 + (size_t)ks * 192 * Hn + j;
    const float4* __restrict__ si = (const float4*)(s_inst + ks * 192);
    const float4* __restrict__ ss = (const float4*)(s_sent + ks * 192);
    #pragma unroll 4
    for (int k4 = 0; k4 < 48; ++k4) {
        const float4 iv = si[k4];
        const float4 sv = ss[k4];
        const float* __restrict__ wa = w1 + (size_t)k4 * 4 * Hn;
        const float* __restrict__ wb = w2 + (size_t)k4 * 4 * Hn;
        a0 = fmaf(iv.x, wa[0],      a0);
        a1 = fmaf(iv.y, wa[Hn],     a1);
        a0 = fmaf(iv.z, wa[2 * Hn], a0);
        a1 = fmaf(iv.w, wa[3 * Hn], a1);
        c0 = fmaf(sv.x, wb[0],      c0);
        c1 = fmaf(sv.y, wb[Hn],     c1);
        c0 = fmaf(sv.z, wb[2 * Hn], c0);
        c1 = fmaf(sv.w, wb[3 * Hn], c1);
    }

    __shared__ float r_a[4][64];
    __shared__ float r_c[4][64];
    r_a[ks][j0] = a0 + a1; r_c[ks][j0] = c0 + c1;
    __syncthreads();
    if (ks == 0) {
        const float A = r_a[0][j0] + r_a[1][j0] + r_a[2][j0] + r_a[3][j0];
        const float C = r_c[0][j0] + r_c[1][j0] + r_c[2][j0] + r_c[3][j0];
        const float g = 1.f / (1.f + expf(-(A + C)));
        o1_out[b * Hn + j] = g * s_inst[j] + (1.f - g) * s_sent[j];
    }
}

// ---------------- Layer 2: o2 = g2*o1 + (1-g2)*typ, written TRANSPOSED as me_t[k][b]
__global__ __launch_bounds__(256) void gate_layer2(
    const int* __restrict__ batch_arg, const int* __restrict__ event_pos,
    const int* __restrict__ mask_indices, const float* __restrict__ type_emb,
    const float* __restrict__ emb_table, const float* __restrict__ W2_1,
    const float* __restrict__ W2_2, const float* __restrict__ o1_in,
    float* __restrict__ me_t)
{
    const int b  = blockIdx.x;
    const int j0 = threadIdx.x & 63;
    const int ks = threadIdx.x >> 6;
    const int j  = blockIdx.y * 64 + j0;

    const int mask = mask_indices[b];
    int estar = -1;
    #pragma unroll
    for (int e = 0; e < En; ++e)
        if (event_pos[b * En + e] == mask && estar < 0) estar = e;
    const int tok = batch_arg[b * Sn + mask];

    __shared__ __align__(16) float s_o1[Hn];
    __shared__ __align__(16) float s_typ[Hn];
    for (int t = threadIdx.x; t < Hn; t += 256) {
        s_o1[t]  = o1_in[b * Hn + t];
        s_typ[t] = type_emb[((size_t)b * Sn + mask) * Hn + t];
    }
    __syncthreads();

    float a0 = 0.f, a1 = 0.f, c0 = 0.f, c1 = 0.f;
    const float* __restrict__ w1 = W2_1 + (size_t)ks * 192 * Hn + j;
    const float* __restrict__ w2 = W2_2 + (size_t)ks * 192 * Hn + j;
    const float4* __restrict__ so = (const float4*)(s_o1  + ks * 192);
    const float4* __restrict__ st = (const float4*)(s_typ + ks * 192);
    #pragma unroll 4
    for (int k4 = 0; k4 < 48; ++k4) {
        const float4 ov = so[k4];
        const float4 tv = st[k4];
        const float* __restrict__ wa = w1 + (size_t)k4 * 4 * Hn;
        const float* __restrict__ wb = w2 + (size_t)k4 * 4 * Hn;
        a0 = fmaf(ov.x, wa[0],      a0);
        a1 = fmaf(ov.y, wa[Hn],     a1);
        a0 = fmaf(ov.z, wa[2 * Hn], a0);
        a1 = fmaf(ov.w, wa[3 * Hn], a1);
        c0 = fmaf(tv.x, wb[0],      c0);
        c1 = fmaf(tv.y, wb[Hn],     c1);
        c0 = fmaf(tv.z, wb[2 * Hn], c0);
        c1 = fmaf(tv.w, wb[3 * Hn], c1);
    }

    __shared__ float r_a[4][64];
    __shared__ float r_c[4][64];
    r_a[ks][j0] = a0 + a1; r_c[ks][j0] = c0 + c1;
    __syncthreads();
    if (ks == 0) {
        const float A = r_a[0][j0] + r_a[1][j0] + r_a[2][j0] + r_a[3][j0];
        const float C = r_c[0][j0] + r_c[1][j0] + r_c[2][j0] + r_c[3][j0];
        const float g = 1.f / (1.f + expf(-(A + C)));
        float o2 = g * s_o1[j] + (1.f - g) * s_typ[j];
        if (estar < 0) o2 = emb_table[(size_t)tok * Hn + j];  // mask row never updated
        me_t[j * Bn + b] = o2;
    }
}

// ---------------- LM head partials: partial[kc][b][v] = sum_{k in chunk} me[k][b]*lm_W[k][v]
// Grid (50, 16) = 800 blocks x 256 threads. Thread = 4 v x ALL 16 b (64-VGPR acc,
// no cross-wave reduce). Block covers a 1024-v tile -> 4 KB CONTIGUOUS per k-row;
// the 50 v-tile blocks of a chunk jointly sweep each 201 KB row end-to-end, so the
// chip-wide read stream is ~16 linear streams (DRAM row-buffer friendly) instead
// of scattered 512 B picks at 201 KB stride (the 0.8-1.7 TB/s plateau of R1-R11).
__global__ __launch_bounds__(256) void lm_head_stream(
    const float* __restrict__ me_t, const float* __restrict__ lm_W,
    float* __restrict__ partial)
{
    __shared__ __align__(16) float s_me[KPB * Bn];   // 3 KB me slice for this chunk

    const int tid = threadIdx.x;
    const int kc  = blockIdx.y;
    const int kb  = kc * KPB;
    const int v0  = blockIdx.x * VT + tid * 4;

    if (tid < KPB * Bn / 4)                          // 192 float4, coalesced
        ((float4*)s_me)[tid] = ((const float4*)(me_t + kb * Bn))[tid];
    __syncthreads();

    float4 acc[Bn];
    #pragma unroll
    for (int i = 0; i < Bn; ++i) acc[i] = make_float4(0.f, 0.f, 0.f, 0.f);

#define FMA4(i, s)                                                            \
    acc[i].x = fmaf(s, wv.x, acc[i].x); acc[i].y = fmaf(s, wv.y, acc[i].y);   \
    acc[i].z = fmaf(s, wv.z, acc[i].z); acc[i].w = fmaf(s, wv.w, acc[i].w);

    if (v0 + 3 < Vn) {
        const float* __restrict__ wp = lm_W + (size_t)kb * Vn + v0;
        #pragma unroll 2
        for (int k = 0; k < KPB; ++k) {
            const float4 wv = *(const float4*)(wp + (size_t)k * Vn);
            const float4* __restrict__ m = (const float4*)(s_me + k * Bn);
            const float4 m0 = m[0], m1 = m[1], m2 = m[2], m3 = m[3];
            FMA4(0,  m0.x) FMA4(1,  m0.y) FMA4(2,  m0.z) FMA4(3,  m0.w)
            FMA4(4,  m1.x) FMA4(5,  m1.y) FMA4(6,  m1.z) FMA4(7,  m1.w)
            FMA4(8,  m2.x) FMA4(9,  m2.y) FMA4(10, m2.z) FMA4(11, m2.w)
            FMA4(12, m3.x) FMA4(13, m3.y) FMA4(14, m3.z) FMA4(15, m3.w)
        }
    } else if (v0 < Vn) {
        // tail (last tile): only .x can be a valid v (v0 = 50264); .yzw -> pad
        const float* __restrict__ wq = lm_W + (size_t)kb * Vn + v0;
        for (int k = 0; k < KPB; ++k) {
            const float wx = wq[(size_t)k * Vn];
            #pragma unroll
            for (int b = 0; b < Bn; ++b)
                acc[b].x = fmaf(s_me[k * Bn + b], wx, acc[b].x);
        }
    }
#undef FMA4

    // coalesced partial stores; pad region (v >= Vn) written but never read
    float* __restrict__ pb = partial + (size_t)(kc * Bn) * VNP + v0;
    #pragma unroll
    for (int b = 0; b < Bn; ++b)
        *(float4*)(pb + (size_t)b * VNP) = acc[b];
}

// ---------------- Reduce: out[b][v] = sum_kc partial[kc][b][v] + lm_b[v]
// Thread = one (b, v); all loads/stores lane-coalesced. 3200 blocks.
__global__ __launch_bounds__(256) void lm_reduce(
    const float* __restrict__ partial, const float* __restrict__ lm_b,
    float* __restrict__ out)
{
    const int idx = blockIdx.x * 256 + threadIdx.x;   // over Bn * VNP
    const int b   = idx / VNP;
    const int v   = idx - b * VNP;
    if (v >= Vn) return;

    float s = 0.f;
    #pragma unroll
    for (int kc = 0; kc < KC; ++kc)
        s += partial[(size_t)(kc * Bn + b) * VNP + v];
    out[(size_t)b * Vn + v] = s + lm_b[v];
}

extern "C" void kernel_launch(void* const* d_in, const int* in_sizes, int n_in,
                              void* d_out, int out_size, void* d_ws, size_t ws_size,
                              hipStream_t stream) {
    const int*   batch_arg    = (const int*)  d_in[0];
    const int*   event_pos    = (const int*)  d_in[1];
    const int*   mask_indices = (const int*)  d_in[2];
    const float* sent_emb     = (const float*)d_in[3];
    const float* type_emb     = (const float*)d_in[4];
    const float* emb_table    = (const float*)d_in[5];
    const float* W1_1         = (const float*)d_in[6];
    const float* W1_2         = (const float*)d_in[7];
    const float* W2_1         = (const float*)d_in[8];
    const float* W2_2         = (const float*)d_in[9];
    const float* lm_W         = (const float*)d_in[10];
    const float* lm_b         = (const float*)d_in[11];
    float* out = (float*)d_out;

    float* o1_ws   = (float*)d_ws;                    // Bn*Hn floats
    float* me_t    = o1_ws + (size_t)Bn * Hn;         // Hn*Bn floats
    float* partial = me_t  + (size_t)Hn * Bn;         // KC*Bn*VNP floats (~52 MB)

    dim3 g12(Bn, Hn / 64);
    gate_layer1<<<g12, 256, 0, stream>>>(batch_arg, event_pos, mask_indices,
                                         sent_emb, emb_table, W1_1, W1_2, o1_ws);
    gate_layer2<<<g12, 256, 0, stream>>>(batch_arg, event_pos, mask_indices,
                                         type_emb, emb_table, W2_1, W2_2, o1_ws, me_t);

    dim3 gs(NVT, KC);
    lm_head_stream<<<gs, 256, 0, stream>>>(me_t, lm_W, partial);
    lm_reduce<<<(Bn * VNP) / 256, 256, 0, stream>>>(partial, lm_b, out);
}